// Round 2
// baseline (414.420 us; speedup 1.0000x reference)
//
#include <hip/hip_runtime.h>
#include <math.h>

// Problem constants
#define BB 512
#define CC 100000

// Precomputed constants:
//  S/(1+ALPHA) = 64/1.1 = 58.18181818...
//  log2(e) = 1.4426950408889634
//  K_MAIN = (64/1.1)*log2(e)        = 83.93862056
//  K_MM   = (64/1.1)*0.1*log2(e)    = 8.393862056
//  K_BIAS = -64*log2(e)             = -92.33248262
//  cos(0.5) = 0.8775825618903728, sin(0.5) = 0.479425538604203
#define K_MAIN 83.93862056f
#define K_MM   8.393862056f
#define K_BIAS -92.33248262f
#define COS05  0.8775825618903728f
#define SIN05  0.479425538604203f
#define SCALE  58.18181818f   // 64/1.1
#define INV_B  (1.0f / 512.0f)

// ws layout (floats): [0]=mean, [1]=std, [2..513]=corr[b], [514..1025]=logit_lab[b]

__global__ __launch_bounds__(512) void stats_kernel(
    const float* __restrict__ costh, const float* __restrict__ eps,
    const int* __restrict__ label, float* __restrict__ ws) {
  const int b = threadIdx.x;  // 512 threads, one per row
  const int lab = label[b];
  const float cth = costh[(size_t)b * CC + lab];
  const float ep  = eps[(size_t)b * CC + lab];
  const float th  = acosf(cth);

  __shared__ float red[8];
  __shared__ float s_mean, s_std;
  const int wave = b >> 6, lane = b & 63;

  // ---- reduce sum(theta) -> mean ----
  float v = th;
  #pragma unroll
  for (int o = 32; o > 0; o >>= 1) v += __shfl_down(v, o, 64);
  if (lane == 0) red[wave] = v;
  __syncthreads();
  if (b == 0) {
    float s = 0.0f;
    #pragma unroll
    for (int i = 0; i < 8; i++) s += red[i];
    s_mean = s * INV_B;
  }
  __syncthreads();
  const float mean = s_mean;

  // ---- reduce sum((theta-mean)^2) -> std (ddof=1) ----
  const float d = th - mean;
  v = d * d;
  #pragma unroll
  for (int o = 32; o > 0; o >>= 1) v += __shfl_down(v, o, 64);
  __syncthreads();            // ensure thread 0 done reading red
  if (lane == 0) red[wave] = v;
  __syncthreads();
  if (b == 0) {
    float s = 0.0f;
    #pragma unroll
    for (int i = 0; i < 8; i++) s += red[i];
    s_std = sqrtf(s / 511.0f);
    ws[0] = mean;
    ws[1] = s_std;
  }
  __syncthreads();
  const float stdv = s_std;

  // ---- per-row label-column quantities ----
  const float sinth = sqrtf(fmaxf(fmaf(-cth, cth, 1.0f), 0.0f));
  // label-column logit: (64/1.1)*(0.1*cth + cos(theta + 0.5))
  const float cpm = fmaf(cth, COS05, -sinth * SIN05);  // cos(theta+0.5)
  const float logit_lab = SCALE * fmaf(0.1f, cth, cpm);
  // arg_lab = log2(e)*(logit_lab - 64) = K_MM*cth + K_MAIN*cpm + K_BIAS
  const float arg_lab = fmaf(K_MM, cth, fmaf(K_MAIN, cpm, K_BIAS));

  // "plain" (non-label formula) value at the label column, to subtract:
  const float delt = fmaf(stdv, ep, mean);
  float sd, cd;
  __sincosf(delt, &sd, &cd);
  const float cmm = fmaf(cth, cd, sinth * sd);  // cos(theta - delt)
  const float arg_plain = fmaf(K_MM, cmm, fmaf(K_MAIN, cth, K_BIAS));

  ws[2 + b]   = __builtin_amdgcn_exp2f(arg_lab) - __builtin_amdgcn_exp2f(arg_plain);
  ws[514 + b] = logit_lab;
}

__device__ __forceinline__ float elem_exp(float cth, float ep, float mean, float stdv) {
  const float sinth = sqrtf(fmaxf(fmaf(-cth, cth, 1.0f), 0.0f));
  const float delt = fmaf(stdv, ep, mean);
  float sd, cd;
  __sincosf(delt, &sd, &cd);
  const float cmm = fmaf(cth, cd, sinth * sd);  // cos(theta - delt)
  // arg = log2(e)*(logit - 64), logit = (64/1.1)*(0.1*cmm + cth)
  const float arg = fmaf(K_MM, cmm, fmaf(K_MAIN, cth, K_BIAS));
  return __builtin_amdgcn_exp2f(arg);
}

__global__ __launch_bounds__(1024) void main_kernel(
    const float* __restrict__ costh, const float* __restrict__ eps,
    const float* __restrict__ ws, float* __restrict__ out) {
  const int b = blockIdx.x;
  const float4* __restrict__ c4 = (const float4*)(costh + (size_t)b * CC);
  const float4* __restrict__ e4 = (const float4*)(eps + (size_t)b * CC);
  const float mean = ws[0];
  const float stdv = ws[1];

  float acc = 0.0f;
  const int NV = CC / 4;  // 25000, exact (100000 % 4 == 0)
  for (int v = threadIdx.x; v < NV; v += 1024) {
    const float4 c = c4[v];
    const float4 e = e4[v];
    acc += elem_exp(c.x, e.x, mean, stdv);
    acc += elem_exp(c.y, e.y, mean, stdv);
    acc += elem_exp(c.z, e.z, mean, stdv);
    acc += elem_exp(c.w, e.w, mean, stdv);
  }

  // block reduce (1024 threads = 16 waves)
  #pragma unroll
  for (int o = 32; o > 0; o >>= 1) acc += __shfl_down(acc, o, 64);
  __shared__ float red[16];
  const int wave = threadIdx.x >> 6, lane = threadIdx.x & 63;
  if (lane == 0) red[wave] = acc;
  __syncthreads();
  if (threadIdx.x == 0) {
    float total = ws[2 + b];  // label-column correction
    #pragma unroll
    for (int i = 0; i < 16; i++) total += red[i];
    // logp_lab = logit_lab - 64 - log(total); loss_b = -logp_lab
    const float loss_b = 64.0f + __logf(total) - ws[514 + b];
    atomicAdd(out, loss_b * INV_B);
  }
}

extern "C" void kernel_launch(void* const* d_in, const int* in_sizes, int n_in,
                              void* d_out, int out_size, void* d_ws, size_t ws_size,
                              hipStream_t stream) {
  const float* costh = (const float*)d_in[0];
  const float* eps   = (const float*)d_in[1];
  const int*   label = (const int*)d_in[2];
  float* out = (float*)d_out;
  float* ws  = (float*)d_ws;

  hipMemsetAsync(out, 0, sizeof(float), stream);
  stats_kernel<<<1, 512, 0, stream>>>(costh, eps, label, ws);
  main_kernel<<<BB, 1024, 0, stream>>>(costh, eps, ws, out);
}

// Round 4
// 409.691 us; speedup vs baseline: 1.0115x; 1.0115x over previous
//
#include <hip/hip_runtime.h>
#include <math.h>

// Problem constants
#define BB 512
#define CC 100000

// Precomputed constants:
//  S/(1+ALPHA) = 64/1.1 = 58.18181818...
//  log2(e) = 1.4426950408889634
//  K_MAIN = (64/1.1)*log2(e)        = 83.93862056
//  K_MM   = (64/1.1)*0.1*log2(e)    = 8.393862056
//  K_BIAS = -64*log2(e)             = -92.33248262
//  cos(0.5) = 0.8775825618903728, sin(0.5) = 0.479425538604203
#define K_MAIN 83.93862056f
#define K_MM   8.393862056f
#define K_BIAS -92.33248262f
#define COS05  0.8775825618903728f
#define SIN05  0.479425538604203f
#define SCALE  58.18181818f   // 64/1.1
#define INV_B  (1.0f / 512.0f)

// ws layout (floats): [0]=mean, [1]=std, [2..513]=corr[b], [514..1025]=logit_lab[b]

__global__ __launch_bounds__(512) void stats_kernel(
    const float* __restrict__ costh, const float* __restrict__ eps,
    const int* __restrict__ label, float* __restrict__ ws,
    float* __restrict__ out) {
  const int b = threadIdx.x;  // 512 threads, one per row
  if (b == 0) *out = 0.0f;    // replaces the hipMemsetAsync dispatch
  const int lab = label[b];
  const float cth = costh[(size_t)b * CC + lab];
  const float ep  = eps[(size_t)b * CC + lab];
  const float th  = acosf(cth);

  __shared__ float red[8];
  __shared__ float s_mean, s_std;
  const int wave = b >> 6, lane = b & 63;

  // ---- reduce sum(theta) -> mean ----
  float v = th;
  #pragma unroll
  for (int o = 32; o > 0; o >>= 1) v += __shfl_down(v, o, 64);
  if (lane == 0) red[wave] = v;
  __syncthreads();
  if (b == 0) {
    float s = 0.0f;
    #pragma unroll
    for (int i = 0; i < 8; i++) s += red[i];
    s_mean = s * INV_B;
  }
  __syncthreads();
  const float mean = s_mean;

  // ---- reduce sum((theta-mean)^2) -> std (ddof=1) ----
  const float d = th - mean;
  v = d * d;
  #pragma unroll
  for (int o = 32; o > 0; o >>= 1) v += __shfl_down(v, o, 64);
  __syncthreads();            // ensure thread 0 done reading red
  if (lane == 0) red[wave] = v;
  __syncthreads();
  if (b == 0) {
    float s = 0.0f;
    #pragma unroll
    for (int i = 0; i < 8; i++) s += red[i];
    s_std = sqrtf(s / 511.0f);
    ws[0] = mean;
    ws[1] = s_std;
  }
  __syncthreads();
  const float stdv = s_std;

  // ---- per-row label-column quantities ----
  const float sinth = sqrtf(fmaxf(fmaf(-cth, cth, 1.0f), 0.0f));
  // label-column logit: (64/1.1)*(0.1*cth + cos(theta + 0.5))
  const float cpm = fmaf(cth, COS05, -sinth * SIN05);  // cos(theta+0.5)
  const float logit_lab = SCALE * fmaf(0.1f, cth, cpm);
  // arg_lab = log2(e)*(logit_lab - 64) = K_MM*cth + K_MAIN*cpm + K_BIAS
  const float arg_lab = fmaf(K_MM, cth, fmaf(K_MAIN, cpm, K_BIAS));

  // "plain" (non-label formula) value at the label column, to subtract:
  const float delt = fmaf(stdv, ep, mean);
  float sd, cd;
  __sincosf(delt, &sd, &cd);
  const float cmm = fmaf(cth, cd, sinth * sd);  // cos(theta - delt)
  const float arg_plain = fmaf(K_MM, cmm, fmaf(K_MAIN, cth, K_BIAS));

  ws[2 + b]   = __builtin_amdgcn_exp2f(arg_lab) - __builtin_amdgcn_exp2f(arg_plain);
  ws[514 + b] = logit_lab;
}

__device__ __forceinline__ float elem_exp(float cth, float ep, float mean, float stdv) {
  const float sinth = sqrtf(fmaxf(fmaf(-cth, cth, 1.0f), 0.0f));
  const float delt = fmaf(stdv, ep, mean);
  float sd, cd;
  __sincosf(delt, &sd, &cd);
  const float cmm = fmaf(cth, cd, sinth * sd);  // cos(theta - delt)
  // arg = log2(e)*(logit - 64), logit = (64/1.1)*(0.1*cmm + cth)
  const float arg = fmaf(K_MM, cmm, fmaf(K_MAIN, cth, K_BIAS));
  return __builtin_amdgcn_exp2f(arg);
}

__device__ __forceinline__ float elem_exp4(float4 c, float4 e, float mean, float stdv) {
  return elem_exp(c.x, e.x, mean, stdv) + elem_exp(c.y, e.y, mean, stdv) +
         elem_exp(c.z, e.z, mean, stdv) + elem_exp(c.w, e.w, mean, stdv);
}

// NV = 25000 float4s per row. 1024 threads, unroll U=4 -> stride 4096.
// 6 full iterations cover 24576; tail of 424 handled by threads 0..423.
__global__ __launch_bounds__(1024) void main_kernel(
    const float* __restrict__ costh, const float* __restrict__ eps,
    const float* __restrict__ ws, float* __restrict__ out) {
  const int b = blockIdx.x;
  const float4* __restrict__ c4 = (const float4*)(costh + (size_t)b * CC);
  const float4* __restrict__ e4 = (const float4*)(eps + (size_t)b * CC);
  const float mean = ws[0];
  const float stdv = ws[1];

  float acc = 0.0f;
  int v = threadIdx.x;
  #pragma unroll 1
  for (int it = 0; it < 6; ++it, v += 4096) {
    // Issue all 8 loads up front for MLP; compute afterwards.
    const float4 c0 = c4[v];
    const float4 c1 = c4[v + 1024];
    const float4 c2 = c4[v + 2048];
    const float4 c3 = c4[v + 3072];
    const float4 e0 = e4[v];
    const float4 e1 = e4[v + 1024];
    const float4 e2 = e4[v + 2048];
    const float4 e3 = e4[v + 3072];
    acc += elem_exp4(c0, e0, mean, stdv);
    acc += elem_exp4(c1, e1, mean, stdv);
    acc += elem_exp4(c2, e2, mean, stdv);
    acc += elem_exp4(c3, e3, mean, stdv);
  }
  // tail: v == threadIdx.x + 24576; 24576 + 424 = 25000
  if (v < 25000) {
    const float4 c = c4[v];
    const float4 e = e4[v];
    acc += elem_exp4(c, e, mean, stdv);
  }

  // block reduce (1024 threads = 16 waves)
  #pragma unroll
  for (int o = 32; o > 0; o >>= 1) acc += __shfl_down(acc, o, 64);
  __shared__ float red[16];
  const int wave = threadIdx.x >> 6, lane = threadIdx.x & 63;
  if (lane == 0) red[wave] = acc;
  __syncthreads();
  if (threadIdx.x == 0) {
    float total = ws[2 + b];  // label-column correction
    #pragma unroll
    for (int i = 0; i < 16; i++) total += red[i];
    // logp_lab = logit_lab - 64 - log(total); loss_b = -logp_lab
    const float loss_b = 64.0f + __logf(total) - ws[514 + b];
    atomicAdd(out, loss_b * INV_B);
  }
}

extern "C" void kernel_launch(void* const* d_in, const int* in_sizes, int n_in,
                              void* d_out, int out_size, void* d_ws, size_t ws_size,
                              hipStream_t stream) {
  const float* costh = (const float*)d_in[0];
  const float* eps   = (const float*)d_in[1];
  const int*   label = (const int*)d_in[2];
  float* out = (float*)d_out;
  float* ws  = (float*)d_ws;

  stats_kernel<<<1, 512, 0, stream>>>(costh, eps, label, ws, out);
  main_kernel<<<BB, 1024, 0, stream>>>(costh, eps, ws, out);
}

// Round 5
// 406.883 us; speedup vs baseline: 1.0185x; 1.0069x over previous
//
#include <hip/hip_runtime.h>
#include <math.h>

// Problem constants
#define BB 512
#define CC 100000

// Precomputed constants:
//  S/(1+ALPHA) = 64/1.1 = 58.18181818...
//  K_MAIN = (64/1.1)*log2(e)        = 83.93862056
//  K_MM   = (64/1.1)*0.1*log2(e)    = 8.393862056
//  K_BIAS = -64*log2(e)             = -92.33248262
#define K_MAIN 83.93862056f
#define K_MM   8.393862056f
#define K_BIAS -92.33248262f
#define COS05  0.8775825618903728f
#define SIN05  0.479425538604203f
#define SCALE  58.18181818f   // 64/1.1
#define INV_B  (1.0f / 512.0f)

// ws layout (floats): [0]=mean, [1]=std, [2..513]=corr[b], [514..1025]=logit_lab[b]

__global__ __launch_bounds__(512) void stats_kernel(
    const float* __restrict__ costh, const float* __restrict__ eps,
    const int* __restrict__ label, float* __restrict__ ws,
    float* __restrict__ out) {
  const int b = threadIdx.x;  // 512 threads, one per row
  if (b == 0) *out = 0.0f;    // replaces the hipMemsetAsync dispatch
  const int lab = label[b];
  const float cth = costh[(size_t)b * CC + lab];
  const float ep  = eps[(size_t)b * CC + lab];
  const float th  = acosf(cth);

  __shared__ float red[8];
  __shared__ float s_mean, s_std;
  const int wave = b >> 6, lane = b & 63;

  // ---- reduce sum(theta) -> mean ----
  float v = th;
  #pragma unroll
  for (int o = 32; o > 0; o >>= 1) v += __shfl_down(v, o, 64);
  if (lane == 0) red[wave] = v;
  __syncthreads();
  if (b == 0) {
    float s = 0.0f;
    #pragma unroll
    for (int i = 0; i < 8; i++) s += red[i];
    s_mean = s * INV_B;
  }
  __syncthreads();
  const float mean = s_mean;

  // ---- reduce sum((theta-mean)^2) -> std (ddof=1) ----
  const float d = th - mean;
  v = d * d;
  #pragma unroll
  for (int o = 32; o > 0; o >>= 1) v += __shfl_down(v, o, 64);
  __syncthreads();            // ensure thread 0 done reading red
  if (lane == 0) red[wave] = v;
  __syncthreads();
  if (b == 0) {
    float s = 0.0f;
    #pragma unroll
    for (int i = 0; i < 8; i++) s += red[i];
    s_std = sqrtf(s / 511.0f);
    ws[0] = mean;
    ws[1] = s_std;
  }
  __syncthreads();
  const float stdv = s_std;

  // ---- per-row label-column quantities ----
  const float sinth = sqrtf(fmaf(-cth, cth, 1.0f));
  // label-column logit: (64/1.1)*(0.1*cth + cos(theta + 0.5))
  const float cpm = fmaf(cth, COS05, -sinth * SIN05);  // cos(theta+0.5)
  const float logit_lab = SCALE * fmaf(0.1f, cth, cpm);
  // arg_lab = log2(e)*(logit_lab - 64) = K_MM*cth + K_MAIN*cpm + K_BIAS
  const float arg_lab = fmaf(K_MM, cth, fmaf(K_MAIN, cpm, K_BIAS));

  // "plain" (non-label formula) value at the label column, to subtract:
  const float delt = fmaf(stdv, ep, mean);
  float sd, cd;
  __sincosf(delt, &sd, &cd);
  const float cmm = fmaf(cth, cd, sinth * sd);  // cos(theta - delt)
  const float arg_plain = fmaf(K_MM, cmm, fmaf(K_MAIN, cth, K_BIAS));

  ws[2 + b]   = __builtin_amdgcn_exp2f(arg_lab) - __builtin_amdgcn_exp2f(arg_plain);
  ws[514 + b] = logit_lab;
}

__device__ __forceinline__ float elem_exp(float cth, float ep, float mean, float stdv) {
  // |cth| <= 0.99 guaranteed -> 1 - cth^2 >= 0.0199, no clamp needed
  const float sinth = sqrtf(fmaf(-cth, cth, 1.0f));
  const float delt = fmaf(stdv, ep, mean);
  float sd, cd;
  __sincosf(delt, &sd, &cd);
  const float cmm = fmaf(cth, cd, sinth * sd);  // cos(theta - delt)
  // arg = log2(e)*(logit - 64), logit = (64/1.1)*(0.1*cmm + cth)
  const float arg = fmaf(K_MM, cmm, fmaf(K_MAIN, cth, K_BIAS));
  return __builtin_amdgcn_exp2f(arg);
}

__device__ __forceinline__ float elem_exp4(float4 c, float4 e, float mean, float stdv) {
  return elem_exp(c.x, e.x, mean, stdv) + elem_exp(c.y, e.y, mean, stdv) +
         elem_exp(c.z, e.z, mean, stdv) + elem_exp(c.w, e.w, mean, stdv);
}

// NV = 25000 float4s per row; 1024 threads.
// Software pipeline: 12 compute rounds of 2 float4-pairs (strides of 1024),
// each round's 4 loads prefetched one round ahead (4 KB in flight per wave).
// 12 rounds x 2048 = 24576; tail of 424 float4s for threads 0..423.
__global__ __launch_bounds__(1024, 4) void main_kernel(
    const float* __restrict__ costh, const float* __restrict__ eps,
    const float* __restrict__ ws, float* __restrict__ out) {
  const int b = blockIdx.x;
  const float4* __restrict__ c4 = (const float4*)(costh + (size_t)b * CC);
  const float4* __restrict__ e4 = (const float4*)(eps + (size_t)b * CC);
  const float mean = ws[0];
  const float stdv = ws[1];

  float acc = 0.0f;
  int v = threadIdx.x;

  // prologue: loads for round 0
  float4 c0 = c4[v];
  float4 c1 = c4[v + 1024];
  float4 e0 = e4[v];
  float4 e1 = e4[v + 1024];

  #pragma unroll 1
  for (int it = 0; it < 11; ++it) {
    const int nv = v + 2048;
    // prefetch round it+1 (stays in flight across the compute below;
    // compiler emits s_waitcnt vmcnt(4) before first use of c0/e0)
    const float4 nc0 = c4[nv];
    const float4 nc1 = c4[nv + 1024];
    const float4 ne0 = e4[nv];
    const float4 ne1 = e4[nv + 1024];
    __builtin_amdgcn_sched_barrier(0);  // pin prefetch above compute
    acc += elem_exp4(c0, e0, mean, stdv);
    acc += elem_exp4(c1, e1, mean, stdv);
    c0 = nc0; c1 = nc1; e0 = ne0; e1 = ne1;
    v = nv;
  }
  // final full round (no prefetch)
  acc += elem_exp4(c0, e0, mean, stdv);
  acc += elem_exp4(c1, e1, mean, stdv);

  // tail: v + 2048 == threadIdx.x + 24576; 24576 + 424 = 25000
  v += 2048;
  if (v < 25000) {
    const float4 c = c4[v];
    const float4 e = e4[v];
    acc += elem_exp4(c, e, mean, stdv);
  }

  // block reduce (1024 threads = 16 waves)
  #pragma unroll
  for (int o = 32; o > 0; o >>= 1) acc += __shfl_down(acc, o, 64);
  __shared__ float red[16];
  const int wave = threadIdx.x >> 6, lane = threadIdx.x & 63;
  if (lane == 0) red[wave] = acc;
  __syncthreads();
  if (threadIdx.x == 0) {
    float total = ws[2 + b];  // label-column correction
    #pragma unroll
    for (int i = 0; i < 16; i++) total += red[i];
    // logp_lab = logit_lab - 64 - log(total); loss_b = -logp_lab
    const float loss_b = 64.0f + __logf(total) - ws[514 + b];
    atomicAdd(out, loss_b * INV_B);
  }
}

extern "C" void kernel_launch(void* const* d_in, const int* in_sizes, int n_in,
                              void* d_out, int out_size, void* d_ws, size_t ws_size,
                              hipStream_t stream) {
  const float* costh = (const float*)d_in[0];
  const float* eps   = (const float*)d_in[1];
  const int*   label = (const int*)d_in[2];
  float* out = (float*)d_out;
  float* ws  = (float*)d_ws;

  stats_kernel<<<1, 512, 0, stream>>>(costh, eps, label, ws, out);
  main_kernel<<<BB, 1024, 0, stream>>>(costh, eps, ws, out);
}